// Round 6
// baseline (362.066 us; speedup 1.0000x reference)
//
#include <hip/hip_runtime.h>
#include <hip/hip_bf16.h>
#include <hip/hip_fp16.h>

typedef __hip_bfloat16 bf16;
typedef unsigned short u16;

#define D 128
#define EDIM 16
#define SQRT_D 11.313708498984761f

typedef short bf16x8 __attribute__((ext_vector_type(8)));
typedef float f32x4 __attribute__((ext_vector_type(4)));
typedef _Float16 h2 __attribute__((ext_vector_type(2)));

// pf (prepped fp32 params) layout, in floats
#define PF_BL    0
#define PF_BR    128
#define PF_WE    256
#define PF_ATT   2304
#define PF_BIAS  2432
#define PF_GAMMA 2560
#define PF_BETA  2688
#define PF_TOTAL 2816

__device__ __forceinline__ u16 f2bf_bits(float f) {
    union { bf16 h; u16 s; } cv; cv.h = __float2bfloat16(f); return cv.s;
}
__device__ __forceinline__ float2 h2f2(unsigned u) {
    union { unsigned u; __half2 h; } cv; cv.u = u;
    return __half22float2(cv.h);
}
// XOR-swizzled index for W^T bf16 tiles: row nn (output channel), col k.
__device__ __forceinline__ int swid(int nn, int k) {
    return nn * 128 + ((((k >> 3) ^ (nn & 15)) << 3) | (k & 7));
}
// 8-lane all-reduce sum via DPP (xor1, xor2, half-mirror) — stays in 8-group
__device__ __forceinline__ float red8(float x) {
    x += __int_as_float(__builtin_amdgcn_update_dpp(0, __float_as_int(x), 0xB1, 0xf, 0xf, true));
    x += __int_as_float(__builtin_amdgcn_update_dpp(0, __float_as_int(x), 0x4E, 0xf, 0xf, true));
    x += __int_as_float(__builtin_amdgcn_update_dpp(0, __float_as_int(x), 0x141, 0xf, 0xf, true));
    return x;
}

// ------------------- zero fill (deg + bnsum + bnsumsq) + dtype detect
__global__ void k_zero_detect(int* p, int count, const u16* __restrict__ u, int* flag)
{
    int i = blockIdx.x * blockDim.x + threadIdx.x;
    if (i < count) p[i] = 0;
    if (blockIdx.x == 0) {
        __shared__ int sh[256];
        int t = threadIdx.x;
        int cnt = 0;
        for (int k = t; k < 4096; k += 256) {
            int e = (u[k] >> 7) & 0xFF;
            cnt += (e > 132 && e < 255) ? 1 : 0;
        }
        sh[t] = cnt;
        __syncthreads();
        for (int s = 128; s > 0; s >>= 1) {
            if (t < s) sh[t] += sh[t + s];
            __syncthreads();
        }
        if (t == 0) *flag = (sh[0] > 100) ? 1 : 0;
    }
}

__device__ __forceinline__ float rdv(const void* p, int i, int fl) {
    return fl ? ((const float*)p)[i] : __bfloat162float(((const bf16*)p)[i]);
}

// -- prep (emb->bf16 x8, W^T->bf16 swizzled, params->f32) + dst histogram
__global__ __launch_bounds__(256) void k_prep_hist(
    const void* emb, const void* Wl, const void* Wr,
    const void* bl, const void* br, const void* We, const void* att,
    const void* bias, const void* gamma, const void* beta,
    const int* __restrict__ flag, u16* __restrict__ emb16,
    u16* __restrict__ WT, float* __restrict__ pf,
    const int* __restrict__ ei, int* __restrict__ deg,
    int nE, int embCount, int prepBlocks)
{
    if ((int)blockIdx.x >= prepBlocks) {              // fused dst histogram
        int e = (blockIdx.x - prepBlocks) * 256 + threadIdx.x;
        if (e < nE) atomicAdd(&deg[ei[nE + e]], 1);
        return;
    }
    const int fl = *flag;
    int idx = blockIdx.x * 256 + threadIdx.x;
    const int embV = (embCount + 7) >> 3;
    if (idx < embV) {                     // 8 emb elems per thread
        int base = idx << 3;
        int lim = min(8, embCount - base);
        if (lim == 8) {
            u16 o[8];
            if (fl) {
                float f[8];
                const float4* s = (const float4*)((const float*)emb + base);
                *(float4*)(f)     = s[0];
                *(float4*)(f + 4) = s[1];
                #pragma unroll
                for (int k = 0; k < 8; ++k) o[k] = f2bf_bits(f[k] * SQRT_D);
            } else {
                u16 uu[8];
                *(uint4*)uu = *(const uint4*)((const u16*)emb + base);
                #pragma unroll
                for (int k = 0; k < 8; ++k) {
                    float v = __uint_as_float(((unsigned)uu[k]) << 16);
                    o[k] = f2bf_bits(v * SQRT_D);
                }
            }
            *(uint4*)(emb16 + base) = *(uint4*)o;
        } else {
            for (int k = 0; k < lim; ++k)
                emb16[base + k] = f2bf_bits(rdv(emb, base + k, fl) * SQRT_D);
        }
        return;
    }
    idx -= embV;
    if (idx < 32768) {            // W transpose: w=idx>>14, j=idx&16383
        int w = idx >> 14;
        int j = idx & 16383;
        int k = j >> 7, nn = j & 127;
        const void* W = w ? Wr : Wl;
        WT[w * 16384 + swid(nn, k)] = f2bf_bits(rdv(W, k * D + nn, fl));
        return;
    }
    idx -= 32768;
    if (idx < 128)  { pf[PF_BL + idx] = rdv(bl, idx, fl); return; }
    idx -= 128;
    if (idx < 128)  { pf[PF_BR + idx] = rdv(br, idx, fl); return; }
    idx -= 128;
    if (idx < 2048) { pf[PF_WE + idx] = rdv(We, idx, fl); return; }
    idx -= 2048;
    if (idx < 128)  { pf[PF_ATT + idx] = rdv(att, idx, fl); return; }
    idx -= 128;
    if (idx < 128)  { pf[PF_BIAS + idx] = rdv(bias, idx, fl); return; }
    idx -= 128;
    if (idx < 128)  { pf[PF_GAMMA + idx] = rdv(gamma, idx, fl); return; }
    idx -= 128;
    if (idx < 128)  { pf[PF_BETA + idx] = rdv(beta, idx, fl); return; }
}

// ---------------- single-launch CSR scan: every block redundantly computes
// all chunk sums (L2-hot), scans them, then does its own local scan.
__global__ __launch_bounds__(1024) void k_scan1(
    const int* __restrict__ deg, int* __restrict__ row_ptr,
    int* __restrict__ cursor, int n, int nBlk)
{
    __shared__ int chsum[512];
    __shared__ int part[1024];
    __shared__ int myOff;
    const int t = threadIdx.x;
    const int wv = t >> 6;
    const int lane = t & 63;

    for (int c = wv; c < nBlk; c += 16) {
        int base = c << 10;
        int s = 0;
        for (int k = lane; k < 1024; k += 64) {
            int i = base + k;
            s += (i < n) ? deg[i] : 0;
        }
        #pragma unroll
        for (int m = 1; m < 64; m <<= 1) s += __shfl_xor(s, m);
        if (lane == 0) chsum[c] = s;
    }
    __syncthreads();
    if (t == 0) {
        int run = 0;
        for (int c = 0; c < (int)blockIdx.x; ++c) run += chsum[c];
        myOff = run;
    }
    __syncthreads();

    int i = blockIdx.x * 1024 + t;
    int v = (i < n) ? deg[i] : 0;
    part[t] = v;
    __syncthreads();
    for (int off = 1; off < 1024; off <<= 1) {
        int u = (t >= off) ? part[t - off] : 0;
        __syncthreads();
        part[t] += u;
        __syncthreads();
    }
    if (i < n) {
        int excl = myOff + part[t] - v;
        row_ptr[i] = excl;
        cursor[i] = excl;
        if (i == n - 1) row_ptr[n] = excl + v;
    }
}

// -------------------- fallback 3-phase scan (only if nBlk > 512)
__global__ __launch_bounds__(1024) void k_scan_sum(
    const int* __restrict__ deg, int* __restrict__ blkSum, int n)
{
    __shared__ int sh[1024];
    int t = threadIdx.x;
    int i = blockIdx.x * 1024 + t;
    sh[t] = (i < n) ? deg[i] : 0;
    __syncthreads();
    for (int s = 512; s > 0; s >>= 1) {
        if (t < s) sh[t] += sh[t + s];
        __syncthreads();
    }
    if (t == 0) blkSum[blockIdx.x] = sh[0];
}
__global__ __launch_bounds__(1024) void k_scan_blk(
    const int* __restrict__ blkSum, int* __restrict__ blkOff, int nBlk)
{
    __shared__ int part[1024];
    int t = threadIdx.x;
    int v = (t < nBlk) ? blkSum[t] : 0;
    part[t] = v;
    __syncthreads();
    for (int off = 1; off < 1024; off <<= 1) {
        int u = (t >= off) ? part[t - off] : 0;
        __syncthreads();
        part[t] += u;
        __syncthreads();
    }
    if (t < nBlk) blkOff[t] = part[t] - v;
}
__global__ __launch_bounds__(1024) void k_scan_write(
    const int* __restrict__ deg, const int* __restrict__ blkOff,
    int* __restrict__ row_ptr, int* __restrict__ cursor, int n)
{
    __shared__ int part[1024];
    int t = threadIdx.x;
    int i = blockIdx.x * 1024 + t;
    int v = (i < n) ? deg[i] : 0;
    part[t] = v;
    __syncthreads();
    for (int off = 1; off < 1024; off <<= 1) {
        int u = (t >= off) ? part[t - off] : 0;
        __syncthreads();
        part[t] += u;
        __syncthreads();
    }
    if (i < n) {
        int excl = blkOff[blockIdx.x] + part[t] - v;
        row_ptr[i] = excl;
        cursor[i] = excl;
        if (i == n - 1) row_ptr[n] = excl + v;
    }
}

// -------- CSR scatter: csr[pos]=src byte-offset; ewc[pos]=fp16 ew row.
__global__ __launch_bounds__(256) void k_scatter(
    const int* __restrict__ ei, int* __restrict__ cursor,
    int* __restrict__ csr, const void* __restrict__ ew,
    u16* __restrict__ ewc, const int* __restrict__ flag, int nE)
{
    int e = blockIdx.x * blockDim.x + threadIdx.x;
    if (e >= nE) return;
    int src = ei[e], dst = ei[nE + e];
    int pos = atomicAdd(&cursor[dst], 1);
    csr[pos] = src << 8;                  // src*256 = fp16 xl row byte offset
    __half2 h[8];
    if (*flag) {
        const float4* s = (const float4*)((const float*)ew + (size_t)e * 16);
        float f[16];
        *(float4*)(f)      = s[0];
        *(float4*)(f + 4)  = s[1];
        *(float4*)(f + 8)  = s[2];
        *(float4*)(f + 12) = s[3];
        #pragma unroll
        for (int q = 0; q < 8; ++q)
            h[q] = __float22half2_rn(make_float2(f[2*q], f[2*q+1]));
    } else {
        const uint4* s = (const uint4*)((const u16*)ew + (size_t)e * 16);
        unsigned uu[8];
        *(uint4*)(uu)     = s[0];
        *(uint4*)(uu + 4) = s[1];
        #pragma unroll
        for (int q = 0; q < 8; ++q) {
            float lo = __uint_as_float(uu[q] << 16);
            float hi = __uint_as_float(uu[q] & 0xffff0000u);
            h[q] = __float22half2_rn(make_float2(lo, hi));
        }
    }
    u16* d16 = ewc + ((size_t)pos << 4);
    *(uint4*)d16       = *(uint4*)&h[0];
    *(uint4*)(d16 + 8) = *(uint4*)&h[4];
}

// ------------------- node transform via MFMA 16x16x32_bf16, 64-row tiles
__global__ __launch_bounds__(256) void k_node(
    const int* __restrict__ x, const u16* __restrict__ emb16,
    const u16* __restrict__ WT, const float* __restrict__ pf,
    u16* __restrict__ xl16, u16* __restrict__ xr16, int n)
{
    __shared__ u16 Bt[2][16384];
    const int t = threadIdx.x;
    {   // linear 64 KB copy, conflict-free
        const uint4* s = (const uint4*)WT;
        uint4* dd = (uint4*)&Bt[0][0];
        #pragma unroll
        for (int i = 0; i < 16; ++i) dd[i * 256 + t] = s[i * 256 + t];
    }
    const int l = t & 63;
    const int wv = t >> 6;
    const int m = l & 15;
    const int quad = l >> 4;
    const int R = blockIdx.x * 64;

    int arow = R + wv * 16 + m;
    int tok = (arow < n) ? x[arow] : 0;
    const u16* ap = emb16 + (size_t)tok * D + quad * 8;
    bf16x8 afr[4];
    #pragma unroll
    for (int kk = 0; kk < 4; ++kk) afr[kk] = *(const bf16x8*)(ap + kk * 32);
    __syncthreads();

    #pragma unroll
    for (int w = 0; w < 2; ++w) {
        const float* bb = pf + (w ? PF_BR : PF_BL);
        u16* out = w ? xr16 : xl16;
        f32x4 acc[8];
        #pragma unroll
        for (int nt = 0; nt < 8; ++nt) {
            float bv = bb[nt * 16 + m];
            acc[nt] = f32x4{bv, bv, bv, bv};
        }
        #pragma unroll
        for (int kk = 0; kk < 4; ++kk) {
            #pragma unroll
            for (int nt = 0; nt < 8; ++nt) {
                int blk = (quad + 4 * kk) ^ m;
                bf16x8 bfr = *(const bf16x8*)&Bt[w][(nt * 16 + m) * 128 + blk * 8];
                acc[nt] = __builtin_amdgcn_mfma_f32_16x16x32_bf16(afr[kk], bfr, acc[nt], 0, 0, 0);
            }
        }
        #pragma unroll
        for (int nt = 0; nt < 8; ++nt) {
            int col = nt * 16 + m;
            #pragma unroll
            for (int r = 0; r < 4; ++r) {
                int row = R + wv * 16 + quad * 4 + r;
                if (row < n)
                    out[(size_t)row * D + col] =
                        __half_as_ushort(__float2half(acc[nt][r]));
            }
        }
    }
}

// per-edge ew row (fp16, 32 B) from CSR-ordered sequential stream
struct EwH {
    unsigned v[8];
    __device__ __forceinline__ void load(const u16* base, int j) {
        const uint4* q = (const uint4*)(base + ((size_t)j << 4));
        uint4 A = q[0], B = q[1];
        v[0]=A.x; v[1]=A.y; v[2]=A.z; v[3]=A.w;
        v[4]=B.x; v[5]=B.y; v[6]=B.z; v[7]=B.w;
    }
    __device__ __forceinline__ float2 pair(int q) const { return h2f2(v[q]); }
};

// ---------------- node-centric aggregation: 1 wave = 4 fixed nodes, flat
// 6-deep edge pipeline across node boundaries. lane l owns channels 2l,2l+1.
__global__ __launch_bounds__(256) void k_agg(
    const int* __restrict__ row_ptr, const int* __restrict__ csr,
    const u16* __restrict__ ewc, const float* __restrict__ pf,
    const u16* __restrict__ xl16, const u16* __restrict__ xr16,
    float* __restrict__ vpre, float* __restrict__ bnsum,
    float* __restrict__ bnsumsq, int n)
{
    const int t = threadIdx.x;
    const int l = t & 63;
    const int wv = __builtin_amdgcn_readfirstlane(t >> 6);

#if __has_builtin(__builtin_amdgcn_fdot2)
    h2 we0[8], we1[8];
    #pragma unroll
    for (int q = 0; q < 8; ++q) {
        float2 a = *(const float2*)&pf[PF_WE + (2*q)   * D + 2 * l];
        float2 b = *(const float2*)&pf[PF_WE + (2*q+1) * D + 2 * l];
        we0[q] = h2{(_Float16)a.x, (_Float16)b.x};
        we1[q] = h2{(_Float16)a.y, (_Float16)b.y};
    }
#else
    float2 we[EDIM];
    #pragma unroll
    for (int k = 0; k < EDIM; ++k)
        we[k] = *(const float2*)&pf[PF_WE + k * D + 2 * l];
#endif
    const float2 attv  = *(const float2*)&pf[PF_ATT + 2 * l];
    const float2 biasv = *(const float2*)&pf[PF_BIAS + 2 * l];

    float s0 = 0, s20 = 0, s1 = 0, s21 = 0;

    const int slot = blockIdx.x * 4 + wv;
    const int i0 = slot * 4;
    const int i1 = min(i0 + 4, n);

    if (i0 < n) {
        const char* xlB = (const char*)xl16 + 4 * l;
        const char* xrB = (const char*)xr16 + 4 * l;

        int cur = i0;
        int endCur  = row_ptr[i0 + 1];
        int endNext = row_ptr[min(i0 + 2, i1)];
        const int begAll = row_ptr[i0];
        const int endAll = row_ptr[i1];

        float2 xrvCur  = h2f2(*(const unsigned*)(xrB + ((size_t)i0 << 8)));
        int nxt0 = min(i0 + 1, i1 - 1);
        float2 xrvNext = h2f2(*(const unsigned*)(xrB + ((size_t)nxt0 << 8)));

        float acc0 = 0, acc1 = 0, den = 0;

        auto finalize = [&]() {
            float inv = den > 0.f ? 1.0f / den : 0.0f;
            float v0 = fmaf(acc0, inv, biasv.x);
            float v1 = fmaf(acc1, inv, biasv.y);
            *(float2*)(vpre + ((size_t)cur << 7) + 2 * l) = make_float2(v0, v1);
            s0 += v0; s20 += v0 * v0;
            s1 += v1; s21 += v1 * v1;
            acc0 = acc1 = den = 0.f;
        };
        auto advance = [&]() {
            finalize();
            ++cur;
            endCur  = endNext;
            endNext = row_ptr[min(cur + 2, i1)];
            xrvCur  = xrvNext;
            int nxt = min(cur + 1, i1 - 1);
            xrvNext = h2f2(*(const unsigned*)(xrB + ((size_t)nxt << 8)));
        };
        auto comp = [&](const EwH& w, unsigned xbits) {
            float e0 = xrvCur.x, e1 = xrvCur.y;
#if __has_builtin(__builtin_amdgcn_fdot2)
            #pragma unroll
            for (int q = 0; q < 8; ++q) {
                h2 pr = __builtin_bit_cast(h2, w.v[q]);
                e0 = __builtin_amdgcn_fdot2(pr, we0[q], e0, false);
                e1 = __builtin_amdgcn_fdot2(pr, we1[q], e1, false);
            }
#else
            #pragma unroll
            for (int q = 0; q < 8; ++q) {
                float2 pr = w.pair(q);
                e0 = fmaf(pr.x, we[2*q].x,   e0);
                e0 = fmaf(pr.y, we[2*q+1].x, e0);
                e1 = fmaf(pr.x, we[2*q].y,   e1);
                e1 = fmaf(pr.y, we[2*q+1].y, e1);
            }
#endif
            float2 xc = h2f2(xbits);
            float z0 = xc.x + e0, z1 = xc.y + e1;
            float m0 = fmaxf(z0, 0.2f * z0);      // leaky_relu 0.2
            float m1 = fmaxf(z1, 0.2f * z1);
            float p = red8(fmaf(m1, attv.y, m0 * attv.x));
            float ex = __expf(p);
            den += ex;
            acc0 = fmaf(ex, xc.x, acc0);
            acc1 = fmaf(ex, xc.y, acc1);
        };

        const int cnt = endAll - begAll;
        if (cnt > 0) {
            EwH wA, wB, wC, wD, wE, wF;
            unsigned xA = 0, xB = 0, xC = 0, xD = 0, xE = 0, xF = 0;
            {            wA.load(ewc, begAll);     xA = *(const unsigned*)(xlB + csr[begAll]); }
            if (cnt > 1) { wB.load(ewc, begAll + 1); xB = *(const unsigned*)(xlB + csr[begAll + 1]); }
            if (cnt > 2) { wC.load(ewc, begAll + 2); xC = *(const unsigned*)(xlB + csr[begAll + 2]); }
            if (cnt > 3) { wD.load(ewc, begAll + 3); xD = *(const unsigned*)(xlB + csr[begAll + 3]); }
            if (cnt > 4) { wE.load(ewc, begAll + 4); xE = *(const unsigned*)(xlB + csr[begAll + 4]); }
            if (cnt > 5) { wF.load(ewc, begAll + 5); xF = *(const unsigned*)(xlB + csr[begAll + 5]); }

            int j  = begAll;
            int jp = begAll + 6;
            while (true) {
#define STAGE(W, X)                                                              \
                while (j >= endCur) advance();                                   \
                comp(W, X);                                                      \
                if (jp < endAll) {                                               \
                    W.load(ewc, jp);                                             \
                    X = *(const unsigned*)(xlB + csr[jp]);                       \
                }                                                                \
                ++jp; ++j;                                                       \
                if (j >= endAll) break;
                STAGE(wA, xA)
                STAGE(wB, xB)
                STAGE(wC, xC)
                STAGE(wD, xD)
                STAGE(wE, xE)
                STAGE(wF, xF)
#undef STAGE
            }
        }
        // finalize remaining nodes (last node + trailing zero-degree nodes)
        while (cur < i1) { finalize(); ++cur; }
    }

    __shared__ float sh[4][D], sh2[4][D];
    sh[wv][2*l] = s0;   sh[wv][2*l+1] = s1;
    sh2[wv][2*l] = s20; sh2[wv][2*l+1] = s21;
    __syncthreads();
    if (t < D) {
        float a = 0, a2 = 0;
        #pragma unroll
        for (int q = 0; q < 4; ++q) { a += sh[q][t]; a2 += sh2[q][t]; }
        atomicAdd(&bnsum[t], a);
        atomicAdd(&bnsumsq[t], a2);
    }
}

// ------------------------------------------------------------- finalize
__global__ __launch_bounds__(256) void k_final(
    const float* __restrict__ vpre, const float* __restrict__ pf,
    const float* __restrict__ bnsum, const float* __restrict__ bnsumsq,
    float* __restrict__ out, int n)
{
    int idx = blockIdx.x * 256 + threadIdx.x;
    if (idx >= n * (D / 4)) return;
    int pos = idx * 4;
    int d = pos & (D - 1);
    const float invN = 1.0f / (float)n;
    float4 v  = *(const float4*)(vpre + pos);
    float4 ms = *(const float4*)(bnsum + d);
    float4 m2 = *(const float4*)(bnsumsq + d);
    float4 g  = *(const float4*)(pf + PF_GAMMA + d);
    float4 bt = *(const float4*)(pf + PF_BETA + d);
    float* vv = (float*)&v; float* msv = (float*)&ms; float* m2v = (float*)&m2;
    float* gv = (float*)&g; float* btv = (float*)&bt;
    float4 o;
    float* ov = (float*)&o;
    #pragma unroll
    for (int c = 0; c < 4; ++c) {
        float mean = msv[c] * invN;
        float var = m2v[c] * invN - mean * mean;
        float y = (vv[c] - mean) * rsqrtf(var + 1e-5f) * gv[c] + btv[c];
        ov[c] = y > 0.f ? y : 0.01f * y;          // leaky_relu 0.01
    }
    *(float4*)(out + pos) = o;
}

// ---------------------------------------------------------------- launch
extern "C" void kernel_launch(void* const* d_in, const int* in_sizes, int n_in,
                              void* d_out, int out_size, void* d_ws, size_t ws_size,
                              hipStream_t stream)
{
    const int*  x     = (const int*)d_in[0];
    const int*  ei    = (const int*)d_in[1];
    const void* ew    = d_in[2];
    const void* emb   = d_in[3];
    const void* Wl    = d_in[4];
    const void* bl    = d_in[5];
    const void* Wr    = d_in[6];
    const void* br    = d_in[7];
    const void* att   = d_in[8];
    const void* We    = d_in[9];
    const void* bias  = d_in[10];
    const void* gamma = d_in[11];
    const void* beta  = d_in[12];

    const int n  = in_sizes[0];
    const int nE = in_sizes[1] / 2;
    const int embCount = in_sizes[3];

    const int nScanBlk = (n + 1023) / 1024;

    float* ws      = (float*)d_ws;
    float* vpre    = ws;
    u16*   xl16    = (u16*)(vpre + (size_t)n * D);
    u16*   xr16    = xl16 + (size_t)n * D;
    int*   deg     = (int*)(xr16 + (size_t)n * D);
    float* bnsum   = (float*)(deg + n);
    float* bnsumsq = bnsum + D;
    int*   flag    = (int*)(bnsumsq + D);
    int*   row_ptr = flag + 1;
    int*   cursor  = row_ptr + (n + 1);
    int*   blkSum  = cursor + n;
    int*   blkOff  = blkSum + nScanBlk;
    uintptr_t p    = (uintptr_t)(blkOff + nScanBlk);
    p = (p + 15) & ~(uintptr_t)15;
    int*   csr     = (int*)p;
    p = (uintptr_t)(csr + nE);
    p = (p + 15) & ~(uintptr_t)15;
    u16*   emb16   = (u16*)p;
    p = (uintptr_t)(emb16 + embCount);
    p = (p + 15) & ~(uintptr_t)15;
    u16*   WT      = (u16*)p;
    p = (uintptr_t)(WT + 32768);
    float* pf      = (float*)p;
    p = (uintptr_t)(pf + PF_TOTAL);
    p = (p + 15) & ~(uintptr_t)15;
    u16*   ewc     = (u16*)p;

    // zero deg + bnsum + bnsumsq (contiguous) and detect dtype, one launch
    int zc = n + 2 * D;
    k_zero_detect<<<(zc + 255) / 256, 256, 0, stream>>>(deg, zc, (const u16*)emb, flag);

    int embV = (embCount + 7) >> 3;
    int prepN = embV + 32768 + PF_TOTAL;
    int prepBlocks = (prepN + 255) / 256;
    int histBlocks = (nE + 255) / 256;
    k_prep_hist<<<prepBlocks + histBlocks, 256, 0, stream>>>(
        emb, Wl, Wr, bl, br, We, att, bias, gamma, beta,
        flag, emb16, WT, pf, ei, deg, nE, embCount, prepBlocks);

    if (nScanBlk <= 512) {
        k_scan1<<<nScanBlk, 1024, 0, stream>>>(deg, row_ptr, cursor, n, nScanBlk);
    } else {
        k_scan_sum<<<nScanBlk, 1024, 0, stream>>>(deg, blkSum, n);
        k_scan_blk<<<1, 1024, 0, stream>>>(blkSum, blkOff, nScanBlk);
        k_scan_write<<<nScanBlk, 1024, 0, stream>>>(deg, blkOff, row_ptr, cursor, n);
    }

    k_scatter<<<histBlocks, 256, 0, stream>>>(ei, cursor, csr, ew, ewc, flag, nE);

    k_node<<<(n + 63) / 64, 256, 0, stream>>>(x, emb16, WT, pf, xl16, xr16, n);

    int aggBlocks = (n + 15) / 16;   // 4 waves x 4 nodes per block
    k_agg<<<aggBlocks, 256, 0, stream>>>(row_ptr, csr, ewc, pf, xl16, xr16,
                                         vpre, bnsum, bnsumsq, n);

    k_final<<<(n * (D / 4) + 255) / 256, 256, 0, stream>>>(
        vpre, pf, bnsum, bnsumsq, (float*)d_out, n);
}

// Round 7
// 348.624 us; speedup vs baseline: 1.0386x; 1.0386x over previous
//
#include <hip/hip_runtime.h>
#include <hip/hip_bf16.h>
#include <hip/hip_fp16.h>

typedef __hip_bfloat16 bf16;
typedef unsigned short u16;

#define D 128
#define EDIM 16
#define SQRT_D 11.313708498984761f

typedef short bf16x8 __attribute__((ext_vector_type(8)));
typedef float f32x4 __attribute__((ext_vector_type(4)));
typedef _Float16 h2 __attribute__((ext_vector_type(2)));

// pf (prepped fp32 params) layout, in floats
#define PF_BL    0
#define PF_BR    128
#define PF_WE    256
#define PF_ATT   2304
#define PF_BIAS  2432
#define PF_GAMMA 2560
#define PF_BETA  2688
#define PF_TOTAL 2816

__device__ __forceinline__ u16 f2bf_bits(float f) {
    union { bf16 h; u16 s; } cv; cv.h = __float2bfloat16(f); return cv.s;
}
__device__ __forceinline__ float2 h2f2(unsigned u) {
    union { unsigned u; __half2 h; } cv; cv.u = u;
    return __half22float2(cv.h);
}
// XOR-swizzled index for W^T bf16 tiles: row nn (output channel), col k.
__device__ __forceinline__ int swid(int nn, int k) {
    return nn * 128 + ((((k >> 3) ^ (nn & 15)) << 3) | (k & 7));
}
// 8-lane all-reduce sum via DPP (xor1, xor2, half-mirror) — stays in 8-group
__device__ __forceinline__ float red8(float x) {
    x += __int_as_float(__builtin_amdgcn_update_dpp(0, __float_as_int(x), 0xB1, 0xf, 0xf, true));
    x += __int_as_float(__builtin_amdgcn_update_dpp(0, __float_as_int(x), 0x4E, 0xf, 0xf, true));
    x += __int_as_float(__builtin_amdgcn_update_dpp(0, __float_as_int(x), 0x141, 0xf, 0xf, true));
    return x;
}

// ------------------- zero fill (deg + bnsum + bnsumsq) + dtype detect
__global__ void k_zero_detect(int* p, int count, const u16* __restrict__ u, int* flag)
{
    int i = blockIdx.x * blockDim.x + threadIdx.x;
    if (i < count) p[i] = 0;
    if (blockIdx.x == 0) {
        __shared__ int sh[256];
        int t = threadIdx.x;
        int cnt = 0;
        for (int k = t; k < 4096; k += 256) {
            int e = (u[k] >> 7) & 0xFF;
            cnt += (e > 132 && e < 255) ? 1 : 0;
        }
        sh[t] = cnt;
        __syncthreads();
        for (int s = 128; s > 0; s >>= 1) {
            if (t < s) sh[t] += sh[t + s];
            __syncthreads();
        }
        if (t == 0) *flag = (sh[0] > 100) ? 1 : 0;
    }
}

__device__ __forceinline__ float rdv(const void* p, int i, int fl) {
    return fl ? ((const float*)p)[i] : __bfloat162float(((const bf16*)p)[i]);
}

// -- prep (W^T->bf16 swizzled, *SQRT_D folded in*, params->f32) + histogram
// emb16 pass removed: k_node reads raw emb; sqrt(D) folded into WT.
__global__ __launch_bounds__(256) void k_prep_hist(
    const void* Wl, const void* Wr,
    const void* bl, const void* br, const void* We, const void* att,
    const void* bias, const void* gamma, const void* beta,
    const int* __restrict__ flag,
    u16* __restrict__ WT, float* __restrict__ pf,
    const int* __restrict__ ei, int* __restrict__ deg,
    int nE, int prepBlocks)
{
    if ((int)blockIdx.x >= prepBlocks) {              // fused dst histogram
        int e = (blockIdx.x - prepBlocks) * 256 + threadIdx.x;
        if (e < nE) atomicAdd(&deg[ei[nE + e]], 1);
        return;
    }
    const int fl = *flag;
    int idx = blockIdx.x * 256 + threadIdx.x;
    if (idx < 32768) {            // W transpose: w=idx>>14, j=idx&16383
        int w = idx >> 14;
        int j = idx & 16383;
        int k = j >> 7, nn = j & 127;
        const void* W = w ? Wr : Wl;
        WT[w * 16384 + swid(nn, k)] = f2bf_bits(rdv(W, k * D + nn, fl) * SQRT_D);
        return;
    }
    idx -= 32768;
    if (idx < 128)  { pf[PF_BL + idx] = rdv(bl, idx, fl); return; }
    idx -= 128;
    if (idx < 128)  { pf[PF_BR + idx] = rdv(br, idx, fl); return; }
    idx -= 128;
    if (idx < 2048) { pf[PF_WE + idx] = rdv(We, idx, fl); return; }
    idx -= 2048;
    if (idx < 128)  { pf[PF_ATT + idx] = rdv(att, idx, fl); return; }
    idx -= 128;
    if (idx < 128)  { pf[PF_BIAS + idx] = rdv(bias, idx, fl); return; }
    idx -= 128;
    if (idx < 128)  { pf[PF_GAMMA + idx] = rdv(gamma, idx, fl); return; }
    idx -= 128;
    if (idx < 128)  { pf[PF_BETA + idx] = rdv(beta, idx, fl); return; }
}

// ---------------- single-launch CSR scan: every block redundantly computes
// all chunk sums (L2-hot), scans them, then does its own local scan.
__global__ __launch_bounds__(1024) void k_scan1(
    const int* __restrict__ deg, int* __restrict__ row_ptr,
    int* __restrict__ cursor, int n, int nBlk)
{
    __shared__ int chsum[512];
    __shared__ int part[1024];
    __shared__ int myOff;
    const int t = threadIdx.x;
    const int wv = t >> 6;
    const int lane = t & 63;

    for (int c = wv; c < nBlk; c += 16) {
        int base = c << 10;
        int s = 0;
        for (int k = lane; k < 1024; k += 64) {
            int i = base + k;
            s += (i < n) ? deg[i] : 0;
        }
        #pragma unroll
        for (int m = 1; m < 64; m <<= 1) s += __shfl_xor(s, m);
        if (lane == 0) chsum[c] = s;
    }
    __syncthreads();
    if (t == 0) {
        int run = 0;
        for (int c = 0; c < (int)blockIdx.x; ++c) run += chsum[c];
        myOff = run;
    }
    __syncthreads();

    int i = blockIdx.x * 1024 + t;
    int v = (i < n) ? deg[i] : 0;
    part[t] = v;
    __syncthreads();
    for (int off = 1; off < 1024; off <<= 1) {
        int u = (t >= off) ? part[t - off] : 0;
        __syncthreads();
        part[t] += u;
        __syncthreads();
    }
    if (i < n) {
        int excl = myOff + part[t] - v;
        row_ptr[i] = excl;
        cursor[i] = excl;
        if (i == n - 1) row_ptr[n] = excl + v;
    }
}

// -------------------- fallback 3-phase scan (only if nBlk > 512)
__global__ __launch_bounds__(1024) void k_scan_sum(
    const int* __restrict__ deg, int* __restrict__ blkSum, int n)
{
    __shared__ int sh[1024];
    int t = threadIdx.x;
    int i = blockIdx.x * 1024 + t;
    sh[t] = (i < n) ? deg[i] : 0;
    __syncthreads();
    for (int s = 512; s > 0; s >>= 1) {
        if (t < s) sh[t] += sh[t + s];
        __syncthreads();
    }
    if (t == 0) blkSum[blockIdx.x] = sh[0];
}
__global__ __launch_bounds__(1024) void k_scan_blk(
    const int* __restrict__ blkSum, int* __restrict__ blkOff, int nBlk)
{
    __shared__ int part[1024];
    int t = threadIdx.x;
    int v = (t < nBlk) ? blkSum[t] : 0;
    part[t] = v;
    __syncthreads();
    for (int off = 1; off < 1024; off <<= 1) {
        int u = (t >= off) ? part[t - off] : 0;
        __syncthreads();
        part[t] += u;
        __syncthreads();
    }
    if (t < nBlk) blkOff[t] = part[t] - v;
}
__global__ __launch_bounds__(1024) void k_scan_write(
    const int* __restrict__ deg, const int* __restrict__ blkOff,
    int* __restrict__ row_ptr, int* __restrict__ cursor, int n)
{
    __shared__ int part[1024];
    int t = threadIdx.x;
    int i = blockIdx.x * 1024 + t;
    int v = (i < n) ? deg[i] : 0;
    part[t] = v;
    __syncthreads();
    for (int off = 1; off < 1024; off <<= 1) {
        int u = (t >= off) ? part[t - off] : 0;
        __syncthreads();
        part[t] += u;
        __syncthreads();
    }
    if (i < n) {
        int excl = blkOff[blockIdx.x] + part[t] - v;
        row_ptr[i] = excl;
        cursor[i] = excl;
        if (i == n - 1) row_ptr[n] = excl + v;
    }
}

// ------- FUSED scatter + node (independent work, one launch, 512 threads)
// blocks [0, scatBlocks): CSR scatter (csr + CSR-ordered fp16 ewc)
// blocks [scatBlocks, +nodeBlocks): MFMA node transform, 128 rows/block,
//   W_l/W_r staged one-at-a-time (32 KB LDS -> 4 blocks/CU at 512 thr).
__global__ __launch_bounds__(512) void k_scatnode(
    const int* __restrict__ ei, int* __restrict__ cursor,
    int* __restrict__ csr, const void* __restrict__ ew,
    u16* __restrict__ ewc, const int* __restrict__ flag, int nE,
    const int* __restrict__ x, const void* __restrict__ emb,
    const u16* __restrict__ WT, const float* __restrict__ pf,
    u16* __restrict__ xl16, u16* __restrict__ xr16, int n, int scatBlocks)
{
    __shared__ u16 Bt[16384];
    const int t = threadIdx.x;

    if ((int)blockIdx.x < scatBlocks) {               // ---- scatter role
        int e = blockIdx.x * 512 + t;
        if (e >= nE) return;
        int src = ei[e], dst = ei[nE + e];
        int pos = atomicAdd(&cursor[dst], 1);
        csr[pos] = src << 8;              // src*256 = fp16 xl row byte offset
        __half2 h[8];
        if (*flag) {
            const float4* s = (const float4*)((const float*)ew + (size_t)e * 16);
            float f[16];
            *(float4*)(f)      = s[0];
            *(float4*)(f + 4)  = s[1];
            *(float4*)(f + 8)  = s[2];
            *(float4*)(f + 12) = s[3];
            #pragma unroll
            for (int q = 0; q < 8; ++q)
                h[q] = __float22half2_rn(make_float2(f[2*q], f[2*q+1]));
        } else {
            const uint4* s = (const uint4*)((const u16*)ew + (size_t)e * 16);
            unsigned uu[8];
            *(uint4*)(uu)     = s[0];
            *(uint4*)(uu + 4) = s[1];
            #pragma unroll
            for (int q = 0; q < 8; ++q) {
                float lo = __uint_as_float(uu[q] << 16);
                float hi = __uint_as_float(uu[q] & 0xffff0000u);
                h[q] = __float22half2_rn(make_float2(lo, hi));
            }
        }
        u16* d16 = ewc + ((size_t)pos << 4);
        *(uint4*)d16       = *(uint4*)&h[0];
        *(uint4*)(d16 + 8) = *(uint4*)&h[4];
        return;
    }

    // ---------------------------------------------------- node role
    const int fl = *flag;
    const int l = t & 63;
    const int wv = t >> 6;                 // 0..7
    const int m = l & 15;
    const int quad = l >> 4;
    const int R = (blockIdx.x - scatBlocks) * 128;

    int arow = R + wv * 16 + m;
    int tok = (arow < n) ? x[arow] : 0;
    bf16x8 afr[4];
    if (!fl) {                             // bf16 input: direct bits
        const u16* ap = (const u16*)emb + (size_t)tok * D + quad * 8;
        #pragma unroll
        for (int kk = 0; kk < 4; ++kk) afr[kk] = *(const bf16x8*)(ap + kk * 32);
    } else {                               // f32 input: cvt to bf16
        const float* ap = (const float*)emb + (size_t)tok * D + quad * 8;
        #pragma unroll
        for (int kk = 0; kk < 4; ++kk) {
            float4 a = *(const float4*)(ap + kk * 32);
            float4 b = *(const float4*)(ap + kk * 32 + 4);
            u16 o[8] = { f2bf_bits(a.x), f2bf_bits(a.y), f2bf_bits(a.z), f2bf_bits(a.w),
                         f2bf_bits(b.x), f2bf_bits(b.y), f2bf_bits(b.z), f2bf_bits(b.w) };
            afr[kk] = *(bf16x8*)o;
        }
    }

    #pragma unroll
    for (int w = 0; w < 2; ++w) {
        {   // stage this W tile (32 KB): 2048 uint4 over 512 threads
            const uint4* s = (const uint4*)(WT + w * 16384);
            uint4* dd = (uint4*)&Bt[0];
            #pragma unroll
            for (int i = 0; i < 4; ++i) dd[i * 512 + t] = s[i * 512 + t];
        }
        __syncthreads();
        const float* bb = pf + (w ? PF_BR : PF_BL);
        u16* out = w ? xr16 : xl16;
        f32x4 acc[8];
        #pragma unroll
        for (int nt = 0; nt < 8; ++nt) {
            float bv = bb[nt * 16 + m];
            acc[nt] = f32x4{bv, bv, bv, bv};
        }
        #pragma unroll
        for (int kk = 0; kk < 4; ++kk) {
            #pragma unroll
            for (int nt = 0; nt < 8; ++nt) {
                int blk = (quad + 4 * kk) ^ m;
                bf16x8 bfr = *(const bf16x8*)&Bt[(nt * 16 + m) * 128 + blk * 8];
                acc[nt] = __builtin_amdgcn_mfma_f32_16x16x32_bf16(afr[kk], bfr, acc[nt], 0, 0, 0);
            }
        }
        #pragma unroll
        for (int nt = 0; nt < 8; ++nt) {
            int col = nt * 16 + m;
            #pragma unroll
            for (int r = 0; r < 4; ++r) {
                int row = R + wv * 16 + quad * 4 + r;
                if (row < n)
                    out[(size_t)row * D + col] =
                        __half_as_ushort(__float2half(acc[nt][r]));
            }
        }
        __syncthreads();                   // before re-staging Bt
    }
}

// per-edge ew row (fp16, 32 B) from CSR-ordered sequential stream
struct EwH {
    unsigned v[8];
    __device__ __forceinline__ void load(const u16* base, int j) {
        const uint4* q = (const uint4*)(base + ((size_t)j << 4));
        uint4 A = q[0], B = q[1];
        v[0]=A.x; v[1]=A.y; v[2]=A.z; v[3]=A.w;
        v[4]=B.x; v[5]=B.y; v[6]=B.z; v[7]=B.w;
    }
    __device__ __forceinline__ float2 pair(int q) const { return h2f2(v[q]); }
};

// ---------------- node-centric aggregation: 1 wave = 4 fixed nodes, flat
// 4-deep edge pipeline across node boundaries. lane l owns channels 2l,2l+1.
__global__ __launch_bounds__(256) void k_agg(
    const int* __restrict__ row_ptr, const int* __restrict__ csr,
    const u16* __restrict__ ewc, const float* __restrict__ pf,
    const u16* __restrict__ xl16, const u16* __restrict__ xr16,
    float* __restrict__ vpre, float* __restrict__ bnsum,
    float* __restrict__ bnsumsq, int n)
{
    const int t = threadIdx.x;
    const int l = t & 63;
    const int wv = __builtin_amdgcn_readfirstlane(t >> 6);

#if __has_builtin(__builtin_amdgcn_fdot2)
    h2 we0[8], we1[8];
    #pragma unroll
    for (int q = 0; q < 8; ++q) {
        float2 a = *(const float2*)&pf[PF_WE + (2*q)   * D + 2 * l];
        float2 b = *(const float2*)&pf[PF_WE + (2*q+1) * D + 2 * l];
        we0[q] = h2{(_Float16)a.x, (_Float16)b.x};
        we1[q] = h2{(_Float16)a.y, (_Float16)b.y};
    }
#else
    float2 we[EDIM];
    #pragma unroll
    for (int k = 0; k < EDIM; ++k)
        we[k] = *(const float2*)&pf[PF_WE + k * D + 2 * l];
#endif
    const float2 attv  = *(const float2*)&pf[PF_ATT + 2 * l];
    const float2 biasv = *(const float2*)&pf[PF_BIAS + 2 * l];

    float s0 = 0, s20 = 0, s1 = 0, s21 = 0;

    const int slot = blockIdx.x * 4 + wv;
    const int i0 = slot * 4;
    const int i1 = min(i0 + 4, n);

    if (i0 < n) {
        const char* xlB = (const char*)xl16 + 4 * l;
        const char* xrB = (const char*)xr16 + 4 * l;

        int cur = i0;
        int endCur  = row_ptr[i0 + 1];
        int endNext = row_ptr[min(i0 + 2, i1)];
        const int begAll = row_ptr[i0];
        const int endAll = row_ptr[i1];

        float2 xrvCur  = h2f2(*(const unsigned*)(xrB + ((size_t)i0 << 8)));
        int nxt0 = min(i0 + 1, i1 - 1);
        float2 xrvNext = h2f2(*(const unsigned*)(xrB + ((size_t)nxt0 << 8)));

        float acc0 = 0, acc1 = 0, den = 0;

        auto finalize = [&]() {
            float inv = den > 0.f ? 1.0f / den : 0.0f;
            float v0 = fmaf(acc0, inv, biasv.x);
            float v1 = fmaf(acc1, inv, biasv.y);
            *(float2*)(vpre + ((size_t)cur << 7) + 2 * l) = make_float2(v0, v1);
            s0 += v0; s20 += v0 * v0;
            s1 += v1; s21 += v1 * v1;
            acc0 = acc1 = den = 0.f;
        };
        auto advance = [&]() {
            finalize();
            ++cur;
            endCur  = endNext;
            endNext = row_ptr[min(cur + 2, i1)];
            xrvCur  = xrvNext;
            int nxt = min(cur + 1, i1 - 1);
            xrvNext = h2f2(*(const unsigned*)(xrB + ((size_t)nxt << 8)));
        };
        auto comp = [&](const EwH& w, unsigned xbits) {
            float e0 = xrvCur.x, e1 = xrvCur.y;
#if __has_builtin(__builtin_amdgcn_fdot2)
            #pragma unroll
            for (int q = 0; q < 8; ++q) {
                h2 pr = __builtin_bit_cast(h2, w.v[q]);
                e0 = __builtin_amdgcn_fdot2(pr, we0[q], e0, false);
                e1 = __builtin_amdgcn_fdot2(pr, we1[q], e1, false);
            }
#else
            #pragma unroll
            for (int q = 0; q < 8; ++q) {
                float2 pr = w.pair(q);
                e0 = fmaf(pr.x, we[2*q].x,   e0);
                e0 = fmaf(pr.y, we[2*q+1].x, e0);
                e1 = fmaf(pr.x, we[2*q].y,   e1);
                e1 = fmaf(pr.y, we[2*q+1].y, e1);
            }
#endif
            float2 xc = h2f2(xbits);
            float z0 = xc.x + e0, z1 = xc.y + e1;
            float m0 = fmaxf(z0, 0.2f * z0);      // leaky_relu 0.2
            float m1 = fmaxf(z1, 0.2f * z1);
            float p = red8(fmaf(m1, attv.y, m0 * attv.x));
            float ex = __expf(p);
            den += ex;
            acc0 = fmaf(ex, xc.x, acc0);
            acc1 = fmaf(ex, xc.y, acc1);
        };

        const int cnt = endAll - begAll;
        if (cnt > 0) {
            EwH wA, wB, wC, wD;
            unsigned xA = 0, xB = 0, xC = 0, xD = 0;
            {            wA.load(ewc, begAll);     xA = *(const unsigned*)(xlB + csr[begAll]); }
            if (cnt > 1) { wB.load(ewc, begAll + 1); xB = *(const unsigned*)(xlB + csr[begAll + 1]); }
            if (cnt > 2) { wC.load(ewc, begAll + 2); xC = *(const unsigned*)(xlB + csr[begAll + 2]); }
            if (cnt > 3) { wD.load(ewc, begAll + 3); xD = *(const unsigned*)(xlB + csr[begAll + 3]); }

            int j  = begAll;
            int jp = begAll + 4;
            while (true) {
#define STAGE(W, X)                                                              \
                while (j >= endCur) advance();                                   \
                comp(W, X);                                                      \
                if (jp < endAll) {                                               \
                    W.load(ewc, jp);                                             \
                    X = *(const unsigned*)(xlB + csr[jp]);                       \
                }                                                                \
                ++jp; ++j;                                                       \
                if (j >= endAll) break;
                STAGE(wA, xA)
                STAGE(wB, xB)
                STAGE(wC, xC)
                STAGE(wD, xD)
#undef STAGE
            }
        }
        // finalize remaining nodes (last node + trailing zero-degree nodes)
        while (cur < i1) { finalize(); ++cur; }
    }

    __shared__ float sh[4][D], sh2[4][D];
    sh[wv][2*l] = s0;   sh[wv][2*l+1] = s1;
    sh2[wv][2*l] = s20; sh2[wv][2*l+1] = s21;
    __syncthreads();
    if (t < D) {
        float a = 0, a2 = 0;
        #pragma unroll
        for (int q = 0; q < 4; ++q) { a += sh[q][t]; a2 += sh2[q][t]; }
        atomicAdd(&bnsum[t], a);
        atomicAdd(&bnsumsq[t], a2);
    }
}

// ------------------------------------------------------------- finalize
__global__ __launch_bounds__(256) void k_final(
    const float* __restrict__ vpre, const float* __restrict__ pf,
    const float* __restrict__ bnsum, const float* __restrict__ bnsumsq,
    float* __restrict__ out, int n)
{
    int idx = blockIdx.x * 256 + threadIdx.x;
    if (idx >= n * (D / 4)) return;
    int pos = idx * 4;
    int d = pos & (D - 1);
    const float invN = 1.0f / (float)n;
    float4 v  = *(const float4*)(vpre + pos);
    float4 ms = *(const float4*)(bnsum + d);
    float4 m2 = *(const float4*)(bnsumsq + d);
    float4 g  = *(const float4*)(pf + PF_GAMMA + d);
    float4 bt = *(const float4*)(pf + PF_BETA + d);
    float* vv = (float*)&v; float* msv = (float*)&ms; float* m2v = (float*)&m2;
    float* gv = (float*)&g; float* btv = (float*)&bt;
    float4 o;
    float* ov = (float*)&o;
    #pragma unroll
    for (int c = 0; c < 4; ++c) {
        float mean = msv[c] * invN;
        float var = m2v[c] * invN - mean * mean;
        float y = (vv[c] - mean) * rsqrtf(var + 1e-5f) * gv[c] + btv[c];
        ov[c] = y > 0.f ? y : 0.01f * y;          // leaky_relu 0.01
    }
    *(float4*)(out + pos) = o;
}

// ---------------------------------------------------------------- launch
extern "C" void kernel_launch(void* const* d_in, const int* in_sizes, int n_in,
                              void* d_out, int out_size, void* d_ws, size_t ws_size,
                              hipStream_t stream)
{
    const int*  x     = (const int*)d_in[0];
    const int*  ei    = (const int*)d_in[1];
    const void* ew    = d_in[2];
    const void* emb   = d_in[3];
    const void* Wl    = d_in[4];
    const void* bl    = d_in[5];
    const void* Wr    = d_in[6];
    const void* br    = d_in[7];
    const void* att   = d_in[8];
    const void* We    = d_in[9];
    const void* bias  = d_in[10];
    const void* gamma = d_in[11];
    const void* beta  = d_in[12];

    const int n  = in_sizes[0];
    const int nE = in_sizes[1] / 2;

    const int nScanBlk = (n + 1023) / 1024;

    float* ws      = (float*)d_ws;
    float* vpre    = ws;
    u16*   xl16    = (u16*)(vpre + (size_t)n * D);
    u16*   xr16    = xl16 + (size_t)n * D;
    int*   deg     = (int*)(xr16 + (size_t)n * D);
    float* bnsum   = (float*)(deg + n);
    float* bnsumsq = bnsum + D;
    int*   flag    = (int*)(bnsumsq + D);
    int*   row_ptr = flag + 1;
    int*   cursor  = row_ptr + (n + 1);
    int*   blkSum  = cursor + n;
    int*   blkOff  = blkSum + nScanBlk;
    uintptr_t p    = (uintptr_t)(blkOff + nScanBlk);
    p = (p + 15) & ~(uintptr_t)15;
    int*   csr     = (int*)p;
    p = (uintptr_t)(csr + nE);
    p = (p + 15) & ~(uintptr_t)15;
    u16*   WT      = (u16*)p;
    p = (uintptr_t)(WT + 32768);
    float* pf      = (float*)p;
    p = (uintptr_t)(pf + PF_TOTAL);
    p = (p + 15) & ~(uintptr_t)15;
    u16*   ewc     = (u16*)p;

    // zero deg + bnsum + bnsumsq (contiguous) and detect dtype, one launch
    int zc = n + 2 * D;
    k_zero_detect<<<(zc + 255) / 256, 256, 0, stream>>>(deg, zc, (const u16*)emb, flag);

    int prepN = 32768 + PF_TOTAL;
    int prepBlocks = (prepN + 255) / 256;
    int histBlocks = (nE + 255) / 256;
    k_prep_hist<<<prepBlocks + histBlocks, 256, 0, stream>>>(
        Wl, Wr, bl, br, We, att, bias, gamma, beta,
        flag, WT, pf, ei, deg, nE, prepBlocks);

    if (nScanBlk <= 512) {
        k_scan1<<<nScanBlk, 1024, 0, stream>>>(deg, row_ptr, cursor, n, nScanBlk);
    } else {
        k_scan_sum<<<nScanBlk, 1024, 0, stream>>>(deg, blkSum, n);
        k_scan_blk<<<1, 1024, 0, stream>>>(blkSum, blkOff, nScanBlk);
        k_scan_write<<<nScanBlk, 1024, 0, stream>>>(deg, blkOff, row_ptr, cursor, n);
    }

    int scatBlocks = (nE + 511) / 512;
    int nodeBlocks = (n + 127) / 128;
    k_scatnode<<<scatBlocks + nodeBlocks, 512, 0, stream>>>(
        ei, cursor, csr, ew, ewc, flag, nE,
        x, emb, WT, pf, xl16, xr16, n, scatBlocks);

    int aggBlocks = (n + 15) / 16;   // 4 waves x 4 nodes per block
    k_agg<<<aggBlocks, 256, 0, stream>>>(row_ptr, csr, ewc, pf, xl16, xr16,
                                         vpre, bnsum, bnsumsq, n);

    k_final<<<(n * (D / 4) + 255) / 256, 256, 0, stream>>>(
        vpre, pf, bnsum, bnsumsq, (float*)d_out, n);
}